// Round 9
// baseline (614.075 us; speedup 1.0000x reference)
//
#include <hip/hip_runtime.h>

#define KK 8192
#define DD 64
#define NN 16384
#define DECAYF 0.99f
#define EPSF 1e-5f
#define BATCHF 32.0f
#define CSPLIT 32
#define CODES_PER_BLK (KK / CSPLIT)       // 256 codes -> 32 KB bf16 LDS tile
#define NCT (CODES_PER_BLK / 16)          // 16 MFMA code-tiles per block
#define TOKS_PER_WAVE 64                  // 4 subtiles of 16 (low VGPR -> 4 waves/SIMD)
#define NSUB 4
#define TOKS_PER_BLK 256                  // 4 waves
#define MARGIN_HALF 1.5f                  // half-score margin (full-score 3.0)
#define LISTCAP 262144u
#define LBUFCAP 1024u

// disc fill: 512 MB split across pass1/pass2 as DEDICATED fill blocks appended
// to the grid (wave-level overlap with compute, m114), not in-loop stores.
#define NCOMPUTE ((NN / TOKS_PER_BLK) * CSPLIT)   // 2048 compute blocks
#define NFILL 512                                  // fill blocks per pass
#define FILLBLK_F4 32768                           // 512 KB per fill block
#define FILL4_PER_THR 128

using short8  = __attribute__((ext_vector_type(8))) short;
using floatx4 = __attribute__((ext_vector_type(4))) float;

// ---- helpers ----
__device__ __forceinline__ unsigned short f2bf(float f) {  // RNE bf16
  unsigned u = __float_as_uint(f);
  return (unsigned short)((u + 0x7FFFu + ((u >> 16) & 1u)) >> 16);
}
__device__ __forceinline__ unsigned ford(float f) {        // order-preserving f32->u32
  unsigned u = __float_as_uint(f);
  return (u & 0x80000000u) ? ~u : (u | 0x80000000u);
}
__device__ __forceinline__ float funord(unsigned u) {
  unsigned b = (u & 0x80000000u) ? (u ^ 0x80000000u) : ~u;
  return __uint_as_float(b);
}

// ---- dedicated streaming zero-fill block body ----
__device__ __forceinline__ void fill_block(float* __restrict__ fill, int fb) {
  const floatx4 z = {0.f, 0.f, 0.f, 0.f};
  floatx4* dpz = (floatx4*)fill + (size_t)fb * FILLBLK_F4 + threadIdx.x;
  #pragma unroll 8
  for (int i = 0; i < FILL4_PER_THR; ++i)
    __builtin_nontemporal_store(z, dpz + i * 256);
}

// ---- fused prep: init workspace + fp32->bf16 convs + exact fp32 code norms ----
__global__ __launch_bounds__(256) void prep_kernel(
    const float4* __restrict__ x4, const float4* __restrict__ cb4,
    uint2* __restrict__ xb2, uint2* __restrict__ cbb2,
    float* __restrict__ c2, float4* __restrict__ sums4,
    unsigned* __restrict__ minc, unsigned long long* __restrict__ best,
    unsigned* __restrict__ cnt) {
  const int i = blockIdx.x * 256 + threadIdx.x;

  {  // conv x: all 262144 float4 groups
    float4 v = x4[i];
    uint2 o;
    o.x = (unsigned)f2bf(v.x) | ((unsigned)f2bf(v.y) << 16);
    o.y = (unsigned)f2bf(v.z) | ((unsigned)f2bf(v.w) << 16);
    xb2[i] = o;
  }
  if (i < KK * DD / 4) {  // conv codebook
    float4 v = cb4[i];
    uint2 o;
    o.x = (unsigned)f2bf(v.x) | ((unsigned)f2bf(v.y) << 16);
    o.y = (unsigned)f2bf(v.z) | ((unsigned)f2bf(v.w) << 16);
    cbb2[i] = o;
  }
  if (i < (KK * DD + KK) / 4) sums4[i] = make_float4(0.f, 0.f, 0.f, 0.f);
  if (i < NN) { minc[i] = 0xFFFFFFFFu; best[i] = ~0ULL; }
  if (i < KK) {  // exact fp32 per-code squared norm
    const float4* r = cb4 + (size_t)i * (DD / 4);
    float s = 0.f;
    #pragma unroll
    for (int j = 0; j < DD / 4; ++j) {
      float4 v = r[j];
      s = fmaf(v.x, v.x, s); s = fmaf(v.y, v.y, s);
      s = fmaf(v.z, v.z, s); s = fmaf(v.w, v.w, s);
    }
    c2[i] = s;
  }
  if (i == 0) *cnt = 0u;
}

// ---- shared LDS staging: 256-code bf16 slice, XOR-swizzled 16B chunks ----
__device__ __forceinline__ void stage_tile(const float4* __restrict__ cbb4,
                                           const float* __restrict__ c2,
                                           int code0, float4* tile, float* c2s) {
  const int tid = threadIdx.x;
  #pragma unroll
  for (int it = 0; it < 8; ++it) {
    int C = it * 256 + tid;          // linear 16B chunk 0..2047
    int r = C >> 3, c = C & 7;
    tile[C] = cbb4[(size_t)(code0 + r) * 8 + (c ^ (r & 7))];
  }
  c2s[tid] = c2[code0 + tid];        // 256 threads = 256 codes
}

// ---- pass 1: bf16 MFMA coarse half-score min per token ----
// NSUB=4 (64 tok/wave): ~90 VGPR -> 4 waves/SIMD, 2048 compute blocks.
// Blocks >= NCOMPUTE are pure fill blocks (256 MB of disc zeros total);
// their store waves co-schedule with the MFMA waves (m114 wave-level overlap).
// Records per-(split,token) local min as order-preserving u16 (ford>>16,
// rounds DOWN in order space -> conservative for pass2 skips).
__global__ __launch_bounds__(256, 4) void pass1_kernel(const unsigned short* __restrict__ xb,
                                                       const float4* __restrict__ cbb4,
                                                       const float* __restrict__ c2,
                                                       unsigned* __restrict__ minc,
                                                       unsigned short* __restrict__ lmin16,
                                                       float* __restrict__ fill) {
  __shared__ float4 tile[CODES_PER_BLK * 8];
  __shared__ float c2s[CODES_PER_BLK];
  if (blockIdx.x >= NCOMPUTE) {        // uniform whole-block branch, no barriers
    fill_block(fill, blockIdx.x - NCOMPUTE);
    return;
  }
  const int lane = threadIdx.x & 63;
  const int wave = threadIdx.x >> 6;
  const int col = lane & 15, q = lane >> 4;
  const int tokbase = (blockIdx.x / CSPLIT) * TOKS_PER_BLK + wave * TOKS_PER_WAVE;
  const int split = blockIdx.x % CSPLIT;
  const int code0 = split * CODES_PER_BLK;

  stage_tile(cbb4, c2, code0, tile, c2s);

  short8 a[NSUB][2];
  #pragma unroll
  for (int s = 0; s < NSUB; ++s)
    #pragma unroll
    for (int kk = 0; kk < 2; ++kk)
      a[s][kk] = *(const short8*)(xb + (size_t)(tokbase + s * 16 + col) * DD + kk * 32 + q * 8);

  float mn[NSUB][4];
  #pragma unroll
  for (int s = 0; s < NSUB; ++s)
    #pragma unroll
    for (int r = 0; r < 4; ++r) mn[s][r] = 3.4e38f;

  __syncthreads();

  #pragma unroll 4
  for (int ct = 0; ct < NCT; ++ct) {
    const int row = ct * 16 + col;
    const int rb = row * 8, rx = row & 7;
    short8 b0 = *(const short8*)&tile[rb + (q ^ rx)];
    short8 b1 = *(const short8*)&tile[rb + ((q + 4) ^ rx)];
    const float hneg = -0.5f * c2s[row];
    #pragma unroll
    for (int s = 0; s < NSUB; ++s) {
      floatx4 acc = {hneg, hneg, hneg, hneg};
      acc = __builtin_amdgcn_mfma_f32_16x16x32_bf16(a[s][0], b0, acc, 0, 0, 0);
      acc = __builtin_amdgcn_mfma_f32_16x16x32_bf16(a[s][1], b1, acc, 0, 0, 0);
      #pragma unroll
      for (int r = 0; r < 4; ++r)
        mn[s][r] = fminf(mn[s][r], -acc[r]);   // half-score = 0.5*c2 - dot
    }
  }

  #pragma unroll
  for (int off = 1; off < 16; off <<= 1)
    #pragma unroll
    for (int s = 0; s < NSUB; ++s)
      #pragma unroll
      for (int r = 0; r < 4; ++r)
        mn[s][r] = fminf(mn[s][r], __shfl_xor(mn[s][r], off, 64));

  if (col == 0) {
    #pragma unroll
    for (int s = 0; s < NSUB; ++s) {
      unsigned f0 = ford(mn[s][0]), f1 = ford(mn[s][1]);
      unsigned f2_ = ford(mn[s][2]), f3 = ford(mn[s][3]);
      uint2 pk;
      pk.x = (f0 >> 16) | (f1 & 0xFFFF0000u);
      pk.y = (f2_ >> 16) | (f3 & 0xFFFF0000u);
      *(uint2*)&lmin16[(size_t)split * NN + tokbase + s * 16 + q * 4] = pk;
      atomicMin(&minc[tokbase + s * 16 + q * 4 + 0], f0);
      atomicMin(&minc[tokbase + s * 16 + q * 4 + 1], f1);
      atomicMin(&minc[tokbase + s * 16 + q * 4 + 2], f2_);
      atomicMin(&minc[tokbase + s * 16 + q * 4 + 3], f3);
    }
  }
}

// ---- pass 2: rescan, flag candidates < global_half_min + MARGIN_HALF ----
// Subtile skip: a 16-token subtile is skipped iff every token provably has no
// candidate in this split (lmin16 > ford(th)>>16  =>  lmin > th, exact since
// pass1's lmin is bit-identical to this pass's recomputed scores).
__global__ __launch_bounds__(256, 4) void pass2_kernel(const unsigned short* __restrict__ xb,
                                                       const float4* __restrict__ cbb4,
                                                       const float* __restrict__ c2,
                                                       const unsigned* __restrict__ minc,
                                                       const unsigned short* __restrict__ lmin16,
                                                       unsigned* __restrict__ cnt,
                                                       unsigned* __restrict__ list,
                                                       float* __restrict__ fill) {
  __shared__ float4 tile[CODES_PER_BLK * 8];
  __shared__ float c2s[CODES_PER_BLK];
  __shared__ unsigned lbuf[LBUFCAP];
  __shared__ unsigned lcnt, gbase;
  if (blockIdx.x >= NCOMPUTE) {        // uniform whole-block branch, no barriers
    fill_block(fill, blockIdx.x - NCOMPUTE);
    return;
  }
  const int lane = threadIdx.x & 63;
  const int wave = threadIdx.x >> 6;
  const int col = lane & 15, q = lane >> 4;
  const int tokbase = (blockIdx.x / CSPLIT) * TOKS_PER_BLK + wave * TOKS_PER_WAVE;
  const int split = blockIdx.x % CSPLIT;
  const int code0 = split * CODES_PER_BLK;

  if (threadIdx.x == 0) lcnt = 0u;
  stage_tile(cbb4, c2, code0, tile, c2s);

  short8 a[NSUB][2];
  #pragma unroll
  for (int s = 0; s < NSUB; ++s)
    #pragma unroll
    for (int kk = 0; kk < 2; ++kk)
      a[s][kk] = *(const short8*)(xb + (size_t)(tokbase + s * 16 + col) * DD + kk * 32 + q * 8);

  float th[NSUB][4];
  #pragma unroll
  for (int s = 0; s < NSUB; ++s)
    #pragma unroll
    for (int r = 0; r < 4; ++r)
      th[s][r] = funord(minc[tokbase + s * 16 + q * 4 + r]) + MARGIN_HALF;

  unsigned act = 0;   // wave-uniform active-subtile mask
  #pragma unroll
  for (int s = 0; s < NSUB; ++s) {
    uint2 pk = *(const uint2*)&lmin16[(size_t)split * NN + tokbase + s * 16 + q * 4];
    bool no0 = (pk.x & 0xFFFFu) > (ford(th[s][0]) >> 16);
    bool no1 = (pk.x >> 16)     > (ford(th[s][1]) >> 16);
    bool no2 = (pk.y & 0xFFFFu) > (ford(th[s][2]) >> 16);
    bool no3 = (pk.y >> 16)     > (ford(th[s][3]) >> 16);
    if (!__all(no0 && no1 && no2 && no3)) act |= 1u << s;
  }

  __syncthreads();

  #pragma unroll 2
  for (int ct = 0; ct < NCT; ++ct) {
    const int row = ct * 16 + col;
    const int rb = row * 8, rx = row & 7;
    short8 b0 = *(const short8*)&tile[rb + (q ^ rx)];
    short8 b1 = *(const short8*)&tile[rb + ((q + 4) ^ rx)];
    const float hneg = -0.5f * c2s[row];
    const int code = code0 + row;
    #pragma unroll
    for (int s = 0; s < NSUB; ++s) {
      if (act & (1u << s)) {   // wave-uniform branch, static reg indexing kept
        floatx4 acc = {hneg, hneg, hneg, hneg};
        acc = __builtin_amdgcn_mfma_f32_16x16x32_bf16(a[s][0], b0, acc, 0, 0, 0);
        acc = __builtin_amdgcn_mfma_f32_16x16x32_bf16(a[s][1], b1, acc, 0, 0, 0);
        #pragma unroll
        for (int r = 0; r < 4; ++r) {
          if (-acc[r] < th[s][r]) {   // rare; same formula as pass1 -> consistent
            unsigned tok = (unsigned)(tokbase + s * 16 + q * 4 + r);
            unsigned p = atomicAdd(&lcnt, 1u);
            if (p < LBUFCAP) lbuf[p] = (tok << 13) | (unsigned)code;
          }
        }
      }
    }
  }

  __syncthreads();
  unsigned m = lcnt > LBUFCAP ? LBUFCAP : lcnt;
  if (threadIdx.x == 0) gbase = atomicAdd(cnt, m);
  __syncthreads();
  for (unsigned i = threadIdx.x; i < m; i += 256) {
    unsigned p = gbase + i;
    if (p < LISTCAP) list[p] = lbuf[i];
  }
}

// ---- exact fp32 refinement; (score,code) packed u64 atomicMin ----
__global__ __launch_bounds__(256) void refine_kernel(const unsigned* __restrict__ cnt,
                                                     const unsigned* __restrict__ list,
                                                     const float* __restrict__ x,
                                                     const float* __restrict__ cb,
                                                     const float* __restrict__ c2,
                                                     unsigned long long* __restrict__ best) {
  unsigned n = *cnt; if (n > LISTCAP) n = LISTCAP;
  for (unsigned i = blockIdx.x * 256 + threadIdx.x; i < n; i += gridDim.x * 256) {
    unsigned e = list[i];
    int tok = (int)(e >> 13), code = (int)(e & 8191u);
    const float4* xr = (const float4*)(x + (size_t)tok * DD);
    const float4* cr = (const float4*)(cb + (size_t)code * DD);
    float d = 0.f;
    #pragma unroll
    for (int j = 0; j < DD / 4; ++j) {
      float4 av = xr[j], bv = cr[j];
      d = fmaf(av.x, bv.x, d); d = fmaf(av.y, bv.y, d);
      d = fmaf(av.z, bv.z, d); d = fmaf(av.w, bv.w, d);
    }
    float sc = fmaf(-2.f, d, c2[code]);
    unsigned long long key = ((unsigned long long)ford(sc) << 32) | (unsigned long long)code;
    atomicMin(&best[tok], key);
  }
}

// ---- per-token finalize (+ one-hot scatter; disc zeroed by pass fill blocks) ----
__global__ __launch_bounds__(256) void tokfin_kernel(const unsigned long long* __restrict__ best,
                                                     const float* __restrict__ x,
                                                     const float* __restrict__ cb,
                                                     float* __restrict__ quant,
                                                     float* __restrict__ counts,
                                                     float* __restrict__ sums,
                                                     float* __restrict__ disc) {
  const int n = blockIdx.x * 4 + (threadIdx.x >> 6);   // grid 4096
  const int d = threadIdx.x & 63;
  const unsigned code = (unsigned)(best[n] & 0xFFFFFFFFULL);
  quant[(size_t)n * DD + d] = cb[(size_t)code * DD + d];
  atomicAdd(&sums[(size_t)code * DD + d], x[(size_t)n * DD + d]);
  if (d == 0) {
    atomicAdd(&counts[code], 1.0f);
    disc[(size_t)n * KK + code] = 1.0f;
  }
}

// ---- EMA finalize ----
__global__ __launch_bounds__(256) void finalize_kernel(
    const float* __restrict__ ema_count, const float* __restrict__ ema_weight,
    const float* __restrict__ counts, const float* __restrict__ sums,
    float* __restrict__ out_count, float* __restrict__ out_weight,
    float* __restrict__ out_cb) {
  const int e4 = blockIdx.x * 256 + threadIdx.x;
  const int k = e4 >> 4;
  float nc = ema_count[k] * DECAYF + counts[k] * (1.f - DECAYF);
  nc = (nc + EPSF) / (BATCHF + (float)KK * EPSF) * BATCHF;
  const float4 ew = ((const float4*)ema_weight)[e4];
  const float4 s  = ((const float4*)sums)[e4];
  float4 nw;
  nw.x = ew.x * DECAYF + s.x * (1.f - DECAYF);
  nw.y = ew.y * DECAYF + s.y * (1.f - DECAYF);
  nw.z = ew.z * DECAYF + s.z * (1.f - DECAYF);
  nw.w = ew.w * DECAYF + s.w * (1.f - DECAYF);
  ((float4*)out_weight)[e4] = nw;
  float4 ncb = make_float4(nw.x / nc, nw.y / nc, nw.z / nc, nw.w / nc);
  ((float4*)out_cb)[e4] = ncb;
  if ((e4 & 15) == 0) out_count[k] = nc;
}

extern "C" void kernel_launch(void* const* d_in, const int* in_sizes, int n_in,
                              void* d_out, int out_size, void* d_ws, size_t ws_size,
                              hipStream_t stream) {
  const float* x  = (const float*)d_in[0];
  const float* cb = (const float*)d_in[1];
  const float* ema_count  = (const float*)d_in[2];
  const float* ema_weight = (const float*)d_in[3];

  float* out        = (float*)d_out;
  float* disc       = out;
  float* quant      = disc + (size_t)NN * KK;
  float* out_count  = quant + (size_t)NN * DD;
  float* out_weight = out_count + KK;
  float* out_cb     = out_weight + (size_t)KK * DD;

  float* ws = (float*)d_ws;
  float*    sums   = ws;
  float*    counts = sums + (size_t)KK * DD;
  float*    c2     = counts + KK;
  unsigned* minc   = (unsigned*)(c2 + KK);
  unsigned long long* best = (unsigned long long*)(minc + NN);
  unsigned* cnt    = (unsigned*)(best + NN);
  unsigned* list   = cnt + 16;
  unsigned short* lmin16 = (unsigned short*)(list + LISTCAP);   // 32*NN u16 = 1 MB
  unsigned short* xb  = lmin16 + (size_t)CSPLIT * NN;
  unsigned short* cbb = xb + (size_t)NN * DD;

  prep_kernel<<<NN * DD / 4 / 256, 256, 0, stream>>>(
      (const float4*)x, (const float4*)cb, (uint2*)xb, (uint2*)cbb,
      c2, (float4*)sums, minc, best, cnt);
  pass1_kernel<<<NCOMPUTE + NFILL, 256, 0, stream>>>(
      xb, (const float4*)cbb, c2, minc, lmin16, disc);
  pass2_kernel<<<NCOMPUTE + NFILL, 256, 0, stream>>>(
      xb, (const float4*)cbb, c2, minc, lmin16, cnt, list,
      disc + (size_t)NN * KK / 2);
  refine_kernel<<<256, 256, 0, stream>>>(cnt, list, x, cb, c2, best);
  tokfin_kernel<<<NN / 4, 256, 0, stream>>>(best, x, cb, quant, counts, sums, disc);
  finalize_kernel<<<KK * DD / 4 / 256, 256, 0, stream>>>(
      ema_count, ema_weight, counts, sums, out_count, out_weight, out_cb);
}

// Round 10
// 582.422 us; speedup vs baseline: 1.0543x; 1.0543x over previous
//
#include <hip/hip_runtime.h>

#define KK 8192
#define DD 64
#define NN 16384
#define DECAYF 0.99f
#define EPSF 1e-5f
#define BATCHF 32.0f
#define CSPLIT 32
#define CODES_PER_BLK (KK / CSPLIT)       // 256 codes -> 32 KB bf16 LDS tile
#define NCT (CODES_PER_BLK / 16)          // 16 MFMA code-tiles per block
#define TOKS_PER_WAVE 64                  // 4 subtiles of 16 (low VGPR -> 4 waves/SIMD)
#define NSUB 4
#define TOKS_PER_BLK 256                  // 4 waves
#define MARGIN_HALF 1.5f                  // half-score margin (full-score 3.0)
#define LISTCAP 262144u
#define LBUFCAP 1024u

// disc fill: 512 MB via dedicated fill blocks INTERLEAVED in dispatch order
// (every 5th block) so store-only waves co-schedule with MFMA waves (m114)
// for the whole pass -- not a serial tail (R9 failure: appended blocks ran
// after compute drained), not per-wave in-loop stores (R5: vmcnt-additive).
#define NGRID 2560                        // 2048 compute + 512 fill
#define FILLBLK_F4 32768                  // 512 KB per fill block
#define FILL4_PER_THR 128

using short8  = __attribute__((ext_vector_type(8))) short;
using floatx4 = __attribute__((ext_vector_type(4))) float;

// ---- helpers ----
__device__ __forceinline__ unsigned short f2bf(float f) {  // RNE bf16
  unsigned u = __float_as_uint(f);
  return (unsigned short)((u + 0x7FFFu + ((u >> 16) & 1u)) >> 16);
}
__device__ __forceinline__ unsigned ford(float f) {        // order-preserving f32->u32
  unsigned u = __float_as_uint(f);
  return (u & 0x80000000u) ? ~u : (u | 0x80000000u);
}
__device__ __forceinline__ float funord(unsigned u) {
  unsigned b = (u & 0x80000000u) ? (u ^ 0x80000000u) : ~u;
  return __uint_as_float(b);
}

// ---- dedicated streaming zero-fill block body ----
__device__ __forceinline__ void fill_block(float* __restrict__ fill, int fb) {
  const floatx4 z = {0.f, 0.f, 0.f, 0.f};
  floatx4* dpz = (floatx4*)fill + (size_t)fb * FILLBLK_F4 + threadIdx.x;
  #pragma unroll 8
  for (int i = 0; i < FILL4_PER_THR; ++i)
    __builtin_nontemporal_store(z, dpz + i * 256);
}

// ---- fused prep: init workspace + fp32->bf16 convs + exact fp32 code norms ----
__global__ __launch_bounds__(256) void prep_kernel(
    const float4* __restrict__ x4, const float4* __restrict__ cb4,
    uint2* __restrict__ xb2, uint2* __restrict__ cbb2,
    float* __restrict__ c2, float4* __restrict__ sums4,
    unsigned* __restrict__ minc, unsigned long long* __restrict__ best,
    unsigned* __restrict__ cnt) {
  const int i = blockIdx.x * 256 + threadIdx.x;

  {  // conv x: all 262144 float4 groups
    float4 v = x4[i];
    uint2 o;
    o.x = (unsigned)f2bf(v.x) | ((unsigned)f2bf(v.y) << 16);
    o.y = (unsigned)f2bf(v.z) | ((unsigned)f2bf(v.w) << 16);
    xb2[i] = o;
  }
  if (i < KK * DD / 4) {  // conv codebook
    float4 v = cb4[i];
    uint2 o;
    o.x = (unsigned)f2bf(v.x) | ((unsigned)f2bf(v.y) << 16);
    o.y = (unsigned)f2bf(v.z) | ((unsigned)f2bf(v.w) << 16);
    cbb2[i] = o;
  }
  if (i < (KK * DD + KK) / 4) sums4[i] = make_float4(0.f, 0.f, 0.f, 0.f);
  if (i < NN) { minc[i] = 0xFFFFFFFFu; best[i] = ~0ULL; }
  if (i < KK) {  // exact fp32 per-code squared norm
    const float4* r = cb4 + (size_t)i * (DD / 4);
    float s = 0.f;
    #pragma unroll
    for (int j = 0; j < DD / 4; ++j) {
      float4 v = r[j];
      s = fmaf(v.x, v.x, s); s = fmaf(v.y, v.y, s);
      s = fmaf(v.z, v.z, s); s = fmaf(v.w, v.w, s);
    }
    c2[i] = s;
  }
  if (i == 0) *cnt = 0u;
}

// ---- shared LDS staging: 256-code bf16 slice, XOR-swizzled 16B chunks ----
__device__ __forceinline__ void stage_tile(const float4* __restrict__ cbb4,
                                           const float* __restrict__ c2,
                                           int code0, float4* tile, float* c2s) {
  const int tid = threadIdx.x;
  #pragma unroll
  for (int it = 0; it < 8; ++it) {
    int C = it * 256 + tid;          // linear 16B chunk 0..2047
    int r = C >> 3, c = C & 7;
    tile[C] = cbb4[(size_t)(code0 + r) * 8 + (c ^ (r & 7))];
  }
  c2s[tid] = c2[code0 + tid];        // 256 threads = 256 codes
}

// ---- block-role mapping: every 5th dispatched block is a fill block ----
// b%5==4 -> fill block (b/5); else compute block (b - b/5).
__device__ __forceinline__ bool block_role(int b, int* idx) {
  if ((b % 5) == 4) { *idx = b / 5; return true; }
  *idx = b - b / 5;
  return false;
}

// ---- pass 1: bf16 MFMA coarse half-score min per token ----
// NSUB=4 (64 tok/wave): ~90 VGPR -> 4 waves/SIMD, compute loop is pure
// (no stores); 512 interleaved fill blocks stream 256 MB of disc zeros.
// Records per-(split,token) local min as order-preserving u16 (ford>>16,
// rounds DOWN in order space -> conservative for pass2 skips).
__global__ __launch_bounds__(256, 4) void pass1_kernel(const unsigned short* __restrict__ xb,
                                                       const float4* __restrict__ cbb4,
                                                       const float* __restrict__ c2,
                                                       unsigned* __restrict__ minc,
                                                       unsigned short* __restrict__ lmin16,
                                                       float* __restrict__ fill) {
  __shared__ float4 tile[CODES_PER_BLK * 8];
  __shared__ float c2s[CODES_PER_BLK];
  int bidx;
  if (block_role(blockIdx.x, &bidx)) {   // uniform whole-block branch
    fill_block(fill, bidx);
    return;
  }
  const int lane = threadIdx.x & 63;
  const int wave = threadIdx.x >> 6;
  const int col = lane & 15, q = lane >> 4;
  const int tokbase = (bidx / CSPLIT) * TOKS_PER_BLK + wave * TOKS_PER_WAVE;
  const int split = bidx % CSPLIT;
  const int code0 = split * CODES_PER_BLK;

  stage_tile(cbb4, c2, code0, tile, c2s);

  short8 a[NSUB][2];
  #pragma unroll
  for (int s = 0; s < NSUB; ++s)
    #pragma unroll
    for (int kk = 0; kk < 2; ++kk)
      a[s][kk] = *(const short8*)(xb + (size_t)(tokbase + s * 16 + col) * DD + kk * 32 + q * 8);

  float mn[NSUB][4];
  #pragma unroll
  for (int s = 0; s < NSUB; ++s)
    #pragma unroll
    for (int r = 0; r < 4; ++r) mn[s][r] = 3.4e38f;

  __syncthreads();

  #pragma unroll 4
  for (int ct = 0; ct < NCT; ++ct) {
    const int row = ct * 16 + col;
    const int rb = row * 8, rx = row & 7;
    short8 b0 = *(const short8*)&tile[rb + (q ^ rx)];
    short8 b1 = *(const short8*)&tile[rb + ((q + 4) ^ rx)];
    const float hneg = -0.5f * c2s[row];
    #pragma unroll
    for (int s = 0; s < NSUB; ++s) {
      floatx4 acc = {hneg, hneg, hneg, hneg};
      acc = __builtin_amdgcn_mfma_f32_16x16x32_bf16(a[s][0], b0, acc, 0, 0, 0);
      acc = __builtin_amdgcn_mfma_f32_16x16x32_bf16(a[s][1], b1, acc, 0, 0, 0);
      #pragma unroll
      for (int r = 0; r < 4; ++r)
        mn[s][r] = fminf(mn[s][r], -acc[r]);   // half-score = 0.5*c2 - dot
    }
  }

  #pragma unroll
  for (int off = 1; off < 16; off <<= 1)
    #pragma unroll
    for (int s = 0; s < NSUB; ++s)
      #pragma unroll
      for (int r = 0; r < 4; ++r)
        mn[s][r] = fminf(mn[s][r], __shfl_xor(mn[s][r], off, 64));

  if (col == 0) {
    #pragma unroll
    for (int s = 0; s < NSUB; ++s) {
      unsigned f0 = ford(mn[s][0]), f1 = ford(mn[s][1]);
      unsigned f2_ = ford(mn[s][2]), f3 = ford(mn[s][3]);
      uint2 pk;
      pk.x = (f0 >> 16) | (f1 & 0xFFFF0000u);
      pk.y = (f2_ >> 16) | (f3 & 0xFFFF0000u);
      *(uint2*)&lmin16[(size_t)split * NN + tokbase + s * 16 + q * 4] = pk;
      atomicMin(&minc[tokbase + s * 16 + q * 4 + 0], f0);
      atomicMin(&minc[tokbase + s * 16 + q * 4 + 1], f1);
      atomicMin(&minc[tokbase + s * 16 + q * 4 + 2], f2_);
      atomicMin(&minc[tokbase + s * 16 + q * 4 + 3], f3);
    }
  }
}

// ---- pass 2: rescan, flag candidates < global_half_min + MARGIN_HALF ----
// Subtile skip: a 16-token subtile is skipped iff every token provably has no
// candidate in this split (lmin16 > ford(th)>>16  =>  lmin > th, exact since
// pass1's lmin is bit-identical to this pass's recomputed scores).
__global__ __launch_bounds__(256, 4) void pass2_kernel(const unsigned short* __restrict__ xb,
                                                       const float4* __restrict__ cbb4,
                                                       const float* __restrict__ c2,
                                                       const unsigned* __restrict__ minc,
                                                       const unsigned short* __restrict__ lmin16,
                                                       unsigned* __restrict__ cnt,
                                                       unsigned* __restrict__ list,
                                                       float* __restrict__ fill) {
  __shared__ float4 tile[CODES_PER_BLK * 8];
  __shared__ float c2s[CODES_PER_BLK];
  __shared__ unsigned lbuf[LBUFCAP];
  __shared__ unsigned lcnt, gbase;
  int bidx;
  if (block_role(blockIdx.x, &bidx)) {   // uniform whole-block branch
    fill_block(fill, bidx);
    return;
  }
  const int lane = threadIdx.x & 63;
  const int wave = threadIdx.x >> 6;
  const int col = lane & 15, q = lane >> 4;
  const int tokbase = (bidx / CSPLIT) * TOKS_PER_BLK + wave * TOKS_PER_WAVE;
  const int split = bidx % CSPLIT;
  const int code0 = split * CODES_PER_BLK;

  if (threadIdx.x == 0) lcnt = 0u;
  stage_tile(cbb4, c2, code0, tile, c2s);

  short8 a[NSUB][2];
  #pragma unroll
  for (int s = 0; s < NSUB; ++s)
    #pragma unroll
    for (int kk = 0; kk < 2; ++kk)
      a[s][kk] = *(const short8*)(xb + (size_t)(tokbase + s * 16 + col) * DD + kk * 32 + q * 8);

  float th[NSUB][4];
  #pragma unroll
  for (int s = 0; s < NSUB; ++s)
    #pragma unroll
    for (int r = 0; r < 4; ++r)
      th[s][r] = funord(minc[tokbase + s * 16 + q * 4 + r]) + MARGIN_HALF;

  unsigned act = 0;   // wave-uniform active-subtile mask
  #pragma unroll
  for (int s = 0; s < NSUB; ++s) {
    uint2 pk = *(const uint2*)&lmin16[(size_t)split * NN + tokbase + s * 16 + q * 4];
    bool no0 = (pk.x & 0xFFFFu) > (ford(th[s][0]) >> 16);
    bool no1 = (pk.x >> 16)     > (ford(th[s][1]) >> 16);
    bool no2 = (pk.y & 0xFFFFu) > (ford(th[s][2]) >> 16);
    bool no3 = (pk.y >> 16)     > (ford(th[s][3]) >> 16);
    if (!__all(no0 && no1 && no2 && no3)) act |= 1u << s;
  }

  __syncthreads();

  #pragma unroll 2
  for (int ct = 0; ct < NCT; ++ct) {
    const int row = ct * 16 + col;
    const int rb = row * 8, rx = row & 7;
    short8 b0 = *(const short8*)&tile[rb + (q ^ rx)];
    short8 b1 = *(const short8*)&tile[rb + ((q + 4) ^ rx)];
    const float hneg = -0.5f * c2s[row];
    const int code = code0 + row;
    #pragma unroll
    for (int s = 0; s < NSUB; ++s) {
      if (act & (1u << s)) {   // wave-uniform branch, static reg indexing kept
        floatx4 acc = {hneg, hneg, hneg, hneg};
        acc = __builtin_amdgcn_mfma_f32_16x16x32_bf16(a[s][0], b0, acc, 0, 0, 0);
        acc = __builtin_amdgcn_mfma_f32_16x16x32_bf16(a[s][1], b1, acc, 0, 0, 0);
        #pragma unroll
        for (int r = 0; r < 4; ++r) {
          if (-acc[r] < th[s][r]) {   // rare; same formula as pass1 -> consistent
            unsigned tok = (unsigned)(tokbase + s * 16 + q * 4 + r);
            unsigned p = atomicAdd(&lcnt, 1u);
            if (p < LBUFCAP) lbuf[p] = (tok << 13) | (unsigned)code;
          }
        }
      }
    }
  }

  __syncthreads();
  unsigned m = lcnt > LBUFCAP ? LBUFCAP : lcnt;
  if (threadIdx.x == 0) gbase = atomicAdd(cnt, m);
  __syncthreads();
  for (unsigned i = threadIdx.x; i < m; i += 256) {
    unsigned p = gbase + i;
    if (p < LISTCAP) list[p] = lbuf[i];
  }
}

// ---- exact fp32 refinement; (score,code) packed u64 atomicMin ----
__global__ __launch_bounds__(256) void refine_kernel(const unsigned* __restrict__ cnt,
                                                     const unsigned* __restrict__ list,
                                                     const float* __restrict__ x,
                                                     const float* __restrict__ cb,
                                                     const float* __restrict__ c2,
                                                     unsigned long long* __restrict__ best) {
  unsigned n = *cnt; if (n > LISTCAP) n = LISTCAP;
  for (unsigned i = blockIdx.x * 256 + threadIdx.x; i < n; i += gridDim.x * 256) {
    unsigned e = list[i];
    int tok = (int)(e >> 13), code = (int)(e & 8191u);
    const float4* xr = (const float4*)(x + (size_t)tok * DD);
    const float4* cr = (const float4*)(cb + (size_t)code * DD);
    float d = 0.f;
    #pragma unroll
    for (int j = 0; j < DD / 4; ++j) {
      float4 av = xr[j], bv = cr[j];
      d = fmaf(av.x, bv.x, d); d = fmaf(av.y, bv.y, d);
      d = fmaf(av.z, bv.z, d); d = fmaf(av.w, bv.w, d);
    }
    float sc = fmaf(-2.f, d, c2[code]);
    unsigned long long key = ((unsigned long long)ford(sc) << 32) | (unsigned long long)code;
    atomicMin(&best[tok], key);
  }
}

// ---- per-token finalize (+ one-hot scatter; disc zeroed by pass fill blocks) ----
__global__ __launch_bounds__(256) void tokfin_kernel(const unsigned long long* __restrict__ best,
                                                     const float* __restrict__ x,
                                                     const float* __restrict__ cb,
                                                     float* __restrict__ quant,
                                                     float* __restrict__ counts,
                                                     float* __restrict__ sums,
                                                     float* __restrict__ disc) {
  const int n = blockIdx.x * 4 + (threadIdx.x >> 6);   // grid 4096
  const int d = threadIdx.x & 63;
  const unsigned code = (unsigned)(best[n] & 0xFFFFFFFFULL);
  quant[(size_t)n * DD + d] = cb[(size_t)code * DD + d];
  atomicAdd(&sums[(size_t)code * DD + d], x[(size_t)n * DD + d]);
  if (d == 0) {
    atomicAdd(&counts[code], 1.0f);
    disc[(size_t)n * KK + code] = 1.0f;
  }
}

// ---- EMA finalize ----
__global__ __launch_bounds__(256) void finalize_kernel(
    const float* __restrict__ ema_count, const float* __restrict__ ema_weight,
    const float* __restrict__ counts, const float* __restrict__ sums,
    float* __restrict__ out_count, float* __restrict__ out_weight,
    float* __restrict__ out_cb) {
  const int e4 = blockIdx.x * 256 + threadIdx.x;
  const int k = e4 >> 4;
  float nc = ema_count[k] * DECAYF + counts[k] * (1.f - DECAYF);
  nc = (nc + EPSF) / (BATCHF + (float)KK * EPSF) * BATCHF;
  const float4 ew = ((const float4*)ema_weight)[e4];
  const float4 s  = ((const float4*)sums)[e4];
  float4 nw;
  nw.x = ew.x * DECAYF + s.x * (1.f - DECAYF);
  nw.y = ew.y * DECAYF + s.y * (1.f - DECAYF);
  nw.z = ew.z * DECAYF + s.z * (1.f - DECAYF);
  nw.w = ew.w * DECAYF + s.w * (1.f - DECAYF);
  ((float4*)out_weight)[e4] = nw;
  float4 ncb = make_float4(nw.x / nc, nw.y / nc, nw.z / nc, nw.w / nc);
  ((float4*)out_cb)[e4] = ncb;
  if ((e4 & 15) == 0) out_count[k] = nc;
}

extern "C" void kernel_launch(void* const* d_in, const int* in_sizes, int n_in,
                              void* d_out, int out_size, void* d_ws, size_t ws_size,
                              hipStream_t stream) {
  const float* x  = (const float*)d_in[0];
  const float* cb = (const float*)d_in[1];
  const float* ema_count  = (const float*)d_in[2];
  const float* ema_weight = (const float*)d_in[3];

  float* out        = (float*)d_out;
  float* disc       = out;
  float* quant      = disc + (size_t)NN * KK;
  float* out_count  = quant + (size_t)NN * DD;
  float* out_weight = out_count + KK;
  float* out_cb     = out_weight + (size_t)KK * DD;

  float* ws = (float*)d_ws;
  float*    sums   = ws;
  float*    counts = sums + (size_t)KK * DD;
  float*    c2     = counts + KK;
  unsigned* minc   = (unsigned*)(c2 + KK);
  unsigned long long* best = (unsigned long long*)(minc + NN);
  unsigned* cnt    = (unsigned*)(best + NN);
  unsigned* list   = cnt + 16;
  unsigned short* lmin16 = (unsigned short*)(list + LISTCAP);   // 32*NN u16 = 1 MB
  unsigned short* xb  = lmin16 + (size_t)CSPLIT * NN;
  unsigned short* cbb = xb + (size_t)NN * DD;

  prep_kernel<<<NN * DD / 4 / 256, 256, 0, stream>>>(
      (const float4*)x, (const float4*)cb, (uint2*)xb, (uint2*)cbb,
      c2, (float4*)sums, minc, best, cnt);
  pass1_kernel<<<NGRID, 256, 0, stream>>>(
      xb, (const float4*)cbb, c2, minc, lmin16, disc);
  pass2_kernel<<<NGRID, 256, 0, stream>>>(
      xb, (const float4*)cbb, c2, minc, lmin16, cnt, list,
      disc + (size_t)NN * KK / 2);
  refine_kernel<<<256, 256, 0, stream>>>(cnt, list, x, cb, c2, best);
  tokfin_kernel<<<NN / 4, 256, 0, stream>>>(best, x, cb, quant, counts, sums, disc);
  finalize_kernel<<<KK * DD / 4 / 256, 256, 0, stream>>>(
      ema_count, ema_weight, counts, sums, out_count, out_weight, out_cb);
}

// Round 12
// 572.801 us; speedup vs baseline: 1.0721x; 1.0168x over previous
//
#include <hip/hip_runtime.h>

#define KK 8192
#define DD 64
#define NN 16384
#define DECAYF 0.99f
#define EPSF 1e-5f
#define BATCHF 32.0f
#define CSPLIT 32
#define CODES_PER_BLK (KK / CSPLIT)       // 256 codes -> 32 KB bf16 LDS tile
#define NCT (CODES_PER_BLK / 16)          // 16 MFMA code-tiles per block
#define TOKS_PER_WAVE 64                  // 4 subtiles of 16 (low VGPR -> 4 waves/SIMD)
#define NSUB 4
#define TOKS_PER_BLK 256                  // 4 waves
#define MARGIN_HALF 1.5f                  // half-score margin (full-score 3.0)
#define LISTCAP 262144u
#define LBUFCAP 1024u

// disc fill: 512 MB split across pass1 (first half) and pass2 (second half),
// interleaved with the ct loop. grid 2048 -> 128 KB per block.
// (Best of three measured placements: in-loop 573.0 vs tail-blocks 614.1 vs
// dispatch-interleaved blocks 582.4 -- fill is BW-additive everywhere.)
#define FILL4_PER_BLK  8192               // float4 per block
#define FILL_PER_CT    2                  // 32 f4/thread over 16 ct iters

using short8  = __attribute__((ext_vector_type(8))) short;
using floatx4 = __attribute__((ext_vector_type(4))) float;

// ---- helpers ----
__device__ __forceinline__ unsigned short f2bf(float f) {  // RNE bf16
  unsigned u = __float_as_uint(f);
  return (unsigned short)((u + 0x7FFFu + ((u >> 16) & 1u)) >> 16);
}
__device__ __forceinline__ unsigned ford(float f) {        // order-preserving f32->u32
  unsigned u = __float_as_uint(f);
  return (u & 0x80000000u) ? ~u : (u | 0x80000000u);
}
__device__ __forceinline__ float funord(unsigned u) {
  unsigned b = (u & 0x80000000u) ? (u ^ 0x80000000u) : ~u;
  return __uint_as_float(b);
}

// ---- fused prep: init workspace + fp32->bf16 convs + exact fp32 code norms ----
__global__ __launch_bounds__(256) void prep_kernel(
    const float4* __restrict__ x4, const float4* __restrict__ cb4,
    uint2* __restrict__ xb2, uint2* __restrict__ cbb2,
    float* __restrict__ c2, float4* __restrict__ sums4,
    unsigned* __restrict__ minc, unsigned long long* __restrict__ best,
    unsigned* __restrict__ cnt) {
  const int i = blockIdx.x * 256 + threadIdx.x;

  {  // conv x: all 262144 float4 groups
    float4 v = x4[i];
    uint2 o;
    o.x = (unsigned)f2bf(v.x) | ((unsigned)f2bf(v.y) << 16);
    o.y = (unsigned)f2bf(v.z) | ((unsigned)f2bf(v.w) << 16);
    xb2[i] = o;
  }
  if (i < KK * DD / 4) {  // conv codebook
    float4 v = cb4[i];
    uint2 o;
    o.x = (unsigned)f2bf(v.x) | ((unsigned)f2bf(v.y) << 16);
    o.y = (unsigned)f2bf(v.z) | ((unsigned)f2bf(v.w) << 16);
    cbb2[i] = o;
  }
  if (i < (KK * DD + KK) / 4) sums4[i] = make_float4(0.f, 0.f, 0.f, 0.f);
  if (i < NN) { minc[i] = 0xFFFFFFFFu; best[i] = ~0ULL; }
  if (i < KK) {  // exact fp32 per-code squared norm
    const float4* r = cb4 + (size_t)i * (DD / 4);
    float s = 0.f;
    #pragma unroll
    for (int j = 0; j < DD / 4; ++j) {
      float4 v = r[j];
      s = fmaf(v.x, v.x, s); s = fmaf(v.y, v.y, s);
      s = fmaf(v.z, v.z, s); s = fmaf(v.w, v.w, s);
    }
    c2[i] = s;
  }
  if (i == 0) *cnt = 0u;
}

// ---- shared LDS staging: 256-code bf16 slice, XOR-swizzled 16B chunks ----
__device__ __forceinline__ void stage_tile(const float4* __restrict__ cbb4,
                                           const float* __restrict__ c2,
                                           int code0, float4* tile, float* c2s) {
  const int tid = threadIdx.x;
  #pragma unroll
  for (int it = 0; it < 8; ++it) {
    int C = it * 256 + tid;          // linear 16B chunk 0..2047
    int r = C >> 3, c = C & 7;
    tile[C] = cbb4[(size_t)(code0 + r) * 8 + (c ^ (r & 7))];
  }
  c2s[tid] = c2[code0 + tid];        // 256 threads = 256 codes
}

// ---- pass 1: bf16 MFMA coarse half-score min per token ----
// NSUB=4 (64 tok/wave): ~90 VGPR -> 4 waves/SIMD, grid 2048, 4 blocks/CU.
// 128 KB disc fill interleaved (2 nt-stores/ct in the ds_read shadow).
// Records per-(split,token) local min as order-preserving u16 (ford>>16,
// rounds DOWN in order space -> conservative for pass2 skips).
__global__ __launch_bounds__(256, 4) void pass1_kernel(const unsigned short* __restrict__ xb,
                                                       const float4* __restrict__ cbb4,
                                                       const float* __restrict__ c2,
                                                       unsigned* __restrict__ minc,
                                                       unsigned short* __restrict__ lmin16,
                                                       float* __restrict__ fill) {
  __shared__ float4 tile[CODES_PER_BLK * 8];
  __shared__ float c2s[CODES_PER_BLK];
  const int lane = threadIdx.x & 63;
  const int wave = threadIdx.x >> 6;
  const int col = lane & 15, q = lane >> 4;
  const int tokbase = (blockIdx.x / CSPLIT) * TOKS_PER_BLK + wave * TOKS_PER_WAVE;
  const int split = blockIdx.x % CSPLIT;
  const int code0 = split * CODES_PER_BLK;

  stage_tile(cbb4, c2, code0, tile, c2s);

  short8 a[NSUB][2];
  #pragma unroll
  for (int s = 0; s < NSUB; ++s)
    #pragma unroll
    for (int kk = 0; kk < 2; ++kk)
      a[s][kk] = *(const short8*)(xb + (size_t)(tokbase + s * 16 + col) * DD + kk * 32 + q * 8);

  float mn[NSUB][4];
  #pragma unroll
  for (int s = 0; s < NSUB; ++s)
    #pragma unroll
    for (int r = 0; r < 4; ++r) mn[s][r] = 3.4e38f;

  const floatx4 z = {0.f, 0.f, 0.f, 0.f};
  floatx4* dpz = (floatx4*)fill + (size_t)blockIdx.x * FILL4_PER_BLK + threadIdx.x;

  __syncthreads();

  #pragma unroll 4
  for (int ct = 0; ct < NCT; ++ct) {
    const int row = ct * 16 + col;
    const int rb = row * 8, rx = row & 7;
    short8 b0 = *(const short8*)&tile[rb + (q ^ rx)];
    short8 b1 = *(const short8*)&tile[rb + ((q + 4) ^ rx)];
    #pragma unroll
    for (int u = 0; u < FILL_PER_CT; ++u)   // issue in the ds_read shadow
      __builtin_nontemporal_store(z, dpz + (ct * FILL_PER_CT + u) * 256);
    const float hneg = -0.5f * c2s[row];
    #pragma unroll
    for (int s = 0; s < NSUB; ++s) {
      floatx4 acc = {hneg, hneg, hneg, hneg};
      acc = __builtin_amdgcn_mfma_f32_16x16x32_bf16(a[s][0], b0, acc, 0, 0, 0);
      acc = __builtin_amdgcn_mfma_f32_16x16x32_bf16(a[s][1], b1, acc, 0, 0, 0);
      #pragma unroll
      for (int r = 0; r < 4; ++r)
        mn[s][r] = fminf(mn[s][r], -acc[r]);   // half-score = 0.5*c2 - dot
    }
  }

  #pragma unroll
  for (int off = 1; off < 16; off <<= 1)
    #pragma unroll
    for (int s = 0; s < NSUB; ++s)
      #pragma unroll
      for (int r = 0; r < 4; ++r)
        mn[s][r] = fminf(mn[s][r], __shfl_xor(mn[s][r], off, 64));

  if (col == 0) {
    #pragma unroll
    for (int s = 0; s < NSUB; ++s) {
      unsigned f0 = ford(mn[s][0]), f1 = ford(mn[s][1]);
      unsigned f2_ = ford(mn[s][2]), f3 = ford(mn[s][3]);
      uint2 pk;
      pk.x = (f0 >> 16) | (f1 & 0xFFFF0000u);
      pk.y = (f2_ >> 16) | (f3 & 0xFFFF0000u);
      *(uint2*)&lmin16[(size_t)split * NN + tokbase + s * 16 + q * 4] = pk;
      atomicMin(&minc[tokbase + s * 16 + q * 4 + 0], f0);
      atomicMin(&minc[tokbase + s * 16 + q * 4 + 1], f1);
      atomicMin(&minc[tokbase + s * 16 + q * 4 + 2], f2_);
      atomicMin(&minc[tokbase + s * 16 + q * 4 + 3], f3);
    }
  }
}

// ---- pass 2: rescan, flag candidates < global_half_min + MARGIN_HALF ----
// Subtile skip: a 16-token subtile is skipped iff every token provably has no
// candidate in this split (lmin16 > ford(th)>>16  =>  lmin > th, exact since
// pass1's lmin is bit-identical to this pass's recomputed scores).
__global__ __launch_bounds__(256, 4) void pass2_kernel(const unsigned short* __restrict__ xb,
                                                       const float4* __restrict__ cbb4,
                                                       const float* __restrict__ c2,
                                                       const unsigned* __restrict__ minc,
                                                       const unsigned short* __restrict__ lmin16,
                                                       unsigned* __restrict__ cnt,
                                                       unsigned* __restrict__ list,
                                                       float* __restrict__ fill) {
  __shared__ float4 tile[CODES_PER_BLK * 8];
  __shared__ float c2s[CODES_PER_BLK];
  __shared__ unsigned lbuf[LBUFCAP];
  __shared__ unsigned lcnt, gbase;
  const int lane = threadIdx.x & 63;
  const int wave = threadIdx.x >> 6;
  const int col = lane & 15, q = lane >> 4;
  const int tokbase = (blockIdx.x / CSPLIT) * TOKS_PER_BLK + wave * TOKS_PER_WAVE;
  const int split = blockIdx.x % CSPLIT;
  const int code0 = split * CODES_PER_BLK;

  if (threadIdx.x == 0) lcnt = 0u;
  stage_tile(cbb4, c2, code0, tile, c2s);

  short8 a[NSUB][2];
  #pragma unroll
  for (int s = 0; s < NSUB; ++s)
    #pragma unroll
    for (int kk = 0; kk < 2; ++kk)
      a[s][kk] = *(const short8*)(xb + (size_t)(tokbase + s * 16 + col) * DD + kk * 32 + q * 8);

  float th[NSUB][4];
  #pragma unroll
  for (int s = 0; s < NSUB; ++s)
    #pragma unroll
    for (int r = 0; r < 4; ++r)
      th[s][r] = funord(minc[tokbase + s * 16 + q * 4 + r]) + MARGIN_HALF;

  unsigned act = 0;   // wave-uniform active-subtile mask
  #pragma unroll
  for (int s = 0; s < NSUB; ++s) {
    uint2 pk = *(const uint2*)&lmin16[(size_t)split * NN + tokbase + s * 16 + q * 4];
    bool no0 = (pk.x & 0xFFFFu) > (ford(th[s][0]) >> 16);
    bool no1 = (pk.x >> 16)     > (ford(th[s][1]) >> 16);
    bool no2 = (pk.y & 0xFFFFu) > (ford(th[s][2]) >> 16);
    bool no3 = (pk.y >> 16)     > (ford(th[s][3]) >> 16);
    if (!__all(no0 && no1 && no2 && no3)) act |= 1u << s;
  }

  const floatx4 z = {0.f, 0.f, 0.f, 0.f};
  floatx4* dpz = (floatx4*)fill + (size_t)blockIdx.x * FILL4_PER_BLK + threadIdx.x;

  __syncthreads();

  #pragma unroll 2
  for (int ct = 0; ct < NCT; ++ct) {
    const int row = ct * 16 + col;
    const int rb = row * 8, rx = row & 7;
    short8 b0 = *(const short8*)&tile[rb + (q ^ rx)];
    short8 b1 = *(const short8*)&tile[rb + ((q + 4) ^ rx)];
    #pragma unroll
    for (int u = 0; u < FILL_PER_CT; ++u)   // unconditional: fill correctness
      __builtin_nontemporal_store(z, dpz + (ct * FILL_PER_CT + u) * 256);
    const float hneg = -0.5f * c2s[row];
    const int code = code0 + row;
    #pragma unroll
    for (int s = 0; s < NSUB; ++s) {
      if (act & (1u << s)) {   // wave-uniform branch, static reg indexing kept
        floatx4 acc = {hneg, hneg, hneg, hneg};
        acc = __builtin_amdgcn_mfma_f32_16x16x32_bf16(a[s][0], b0, acc, 0, 0, 0);
        acc = __builtin_amdgcn_mfma_f32_16x16x32_bf16(a[s][1], b1, acc, 0, 0, 0);
        #pragma unroll
        for (int r = 0; r < 4; ++r) {
          if (-acc[r] < th[s][r]) {   // rare; same formula as pass1 -> consistent
            unsigned tok = (unsigned)(tokbase + s * 16 + q * 4 + r);
            unsigned p = atomicAdd(&lcnt, 1u);
            if (p < LBUFCAP) lbuf[p] = (tok << 13) | (unsigned)code;
          }
        }
      }
    }
  }

  __syncthreads();
  unsigned m = lcnt > LBUFCAP ? LBUFCAP : lcnt;
  if (threadIdx.x == 0) gbase = atomicAdd(cnt, m);
  __syncthreads();
  for (unsigned i = threadIdx.x; i < m; i += 256) {
    unsigned p = gbase + i;
    if (p < LISTCAP) list[p] = lbuf[i];
  }
}

// ---- exact fp32 refinement; (score,code) packed u64 atomicMin ----
__global__ __launch_bounds__(256) void refine_kernel(const unsigned* __restrict__ cnt,
                                                     const unsigned* __restrict__ list,
                                                     const float* __restrict__ x,
                                                     const float* __restrict__ cb,
                                                     const float* __restrict__ c2,
                                                     unsigned long long* __restrict__ best) {
  unsigned n = *cnt; if (n > LISTCAP) n = LISTCAP;
  for (unsigned i = blockIdx.x * 256 + threadIdx.x; i < n; i += gridDim.x * 256) {
    unsigned e = list[i];
    int tok = (int)(e >> 13), code = (int)(e & 8191u);
    const float4* xr = (const float4*)(x + (size_t)tok * DD);
    const float4* cr = (const float4*)(cb + (size_t)code * DD);
    float d = 0.f;
    #pragma unroll
    for (int j = 0; j < DD / 4; ++j) {
      float4 av = xr[j], bv = cr[j];
      d = fmaf(av.x, bv.x, d); d = fmaf(av.y, bv.y, d);
      d = fmaf(av.z, bv.z, d); d = fmaf(av.w, bv.w, d);
    }
    float sc = fmaf(-2.f, d, c2[code]);
    unsigned long long key = ((unsigned long long)ford(sc) << 32) | (unsigned long long)code;
    atomicMin(&best[tok], key);
  }
}

// ---- per-token finalize (+ one-hot scatter; disc zeroed by pass fills) ----
__global__ __launch_bounds__(256) void tokfin_kernel(const unsigned long long* __restrict__ best,
                                                     const float* __restrict__ x,
                                                     const float* __restrict__ cb,
                                                     float* __restrict__ quant,
                                                     float* __restrict__ counts,
                                                     float* __restrict__ sums,
                                                     float* __restrict__ disc) {
  const int n = blockIdx.x * 4 + (threadIdx.x >> 6);   // grid 4096
  const int d = threadIdx.x & 63;
  const unsigned code = (unsigned)(best[n] & 0xFFFFFFFFULL);
  quant[(size_t)n * DD + d] = cb[(size_t)code * DD + d];
  atomicAdd(&sums[(size_t)code * DD + d], x[(size_t)n * DD + d]);
  if (d == 0) {
    atomicAdd(&counts[code], 1.0f);
    disc[(size_t)n * KK + code] = 1.0f;
  }
}

// ---- EMA finalize ----
__global__ __launch_bounds__(256) void finalize_kernel(
    const float* __restrict__ ema_count, const float* __restrict__ ema_weight,
    const float* __restrict__ counts, const float* __restrict__ sums,
    float* __restrict__ out_count, float* __restrict__ out_weight,
    float* __restrict__ out_cb) {
  const int e4 = blockIdx.x * 256 + threadIdx.x;
  const int k = e4 >> 4;
  float nc = ema_count[k] * DECAYF + counts[k] * (1.f - DECAYF);
  nc = (nc + EPSF) / (BATCHF + (float)KK * EPSF) * BATCHF;
  const float4 ew = ((const float4*)ema_weight)[e4];
  const float4 s  = ((const float4*)sums)[e4];
  float4 nw;
  nw.x = ew.x * DECAYF + s.x * (1.f - DECAYF);
  nw.y = ew.y * DECAYF + s.y * (1.f - DECAYF);
  nw.z = ew.z * DECAYF + s.z * (1.f - DECAYF);
  nw.w = ew.w * DECAYF + s.w * (1.f - DECAYF);
  ((float4*)out_weight)[e4] = nw;
  float4 ncb = make_float4(nw.x / nc, nw.y / nc, nw.z / nc, nw.w / nc);
  ((float4*)out_cb)[e4] = ncb;
  if ((e4 & 15) == 0) out_count[k] = nc;
}

extern "C" void kernel_launch(void* const* d_in, const int* in_sizes, int n_in,
                              void* d_out, int out_size, void* d_ws, size_t ws_size,
                              hipStream_t stream) {
  const float* x  = (const float*)d_in[0];
  const float* cb = (const float*)d_in[1];
  const float* ema_count  = (const float*)d_in[2];
  const float* ema_weight = (const float*)d_in[3];

  float* out        = (float*)d_out;
  float* disc       = out;
  float* quant      = disc + (size_t)NN * KK;
  float* out_count  = quant + (size_t)NN * DD;
  float* out_weight = out_count + KK;
  float* out_cb     = out_weight + (size_t)KK * DD;

  float* ws = (float*)d_ws;
  float*    sums   = ws;
  float*    counts = sums + (size_t)KK * DD;
  float*    c2     = counts + KK;
  unsigned* minc   = (unsigned*)(c2 + KK);
  unsigned long long* best = (unsigned long long*)(minc + NN);
  unsigned* cnt    = (unsigned*)(best + NN);
  unsigned* list   = cnt + 16;
  unsigned short* lmin16 = (unsigned short*)(list + LISTCAP);   // 32*NN u16 = 1 MB
  unsigned short* xb  = lmin16 + (size_t)CSPLIT * NN;
  unsigned short* cbb = xb + (size_t)NN * DD;

  prep_kernel<<<NN * DD / 4 / 256, 256, 0, stream>>>(
      (const float4*)x, (const float4*)cb, (uint2*)xb, (uint2*)cbb,
      c2, (float4*)sums, minc, best, cnt);
  pass1_kernel<<<(NN / TOKS_PER_BLK) * CSPLIT, 256, 0, stream>>>(
      xb, (const float4*)cbb, c2, minc, lmin16, disc);
  pass2_kernel<<<(NN / TOKS_PER_BLK) * CSPLIT, 256, 0, stream>>>(
      xb, (const float4*)cbb, c2, minc, lmin16, cnt, list,
      disc + (size_t)NN * KK / 2);
  refine_kernel<<<256, 256, 0, stream>>>(cnt, list, x, cb, c2, best);
  tokfin_kernel<<<NN / 4, 256, 0, stream>>>(best, x, cb, quant, counts, sums, disc);
  finalize_kernel<<<KK * DD / 4 / 256, 256, 0, stream>>>(
      ema_count, ema_weight, counts, sums, out_count, out_weight, out_cb);
}